// Round 10
// baseline (793.678 us; speedup 1.0000x reference)
//
#include <hip/hip_runtime.h>

#define MDIM 8192   // B*S
#define KDIM 4096   // DIN
#define NDIM 11008  // DOUT

#define NBLK_W 1024
#define NBLK_X 2048

typedef float f32x4 __attribute__((ext_vector_type(4)));
typedef float f32x16 __attribute__((ext_vector_type(16)));
typedef short bf16x8 __attribute__((ext_vector_type(8)));
typedef unsigned short us4 __attribute__((ext_vector_type(4)));
typedef unsigned short us8 __attribute__((ext_vector_type(8)));

#define GAS __attribute__((address_space(1)))
#define LAS __attribute__((address_space(3)))

__device__ __forceinline__ unsigned short f2bf(float f) {
  unsigned int u = __builtin_bit_cast(unsigned int, f);
  u += 0x7FFFu + ((u >> 16) & 1u);   // RTNE
  return (unsigned short)(u >> 16);
}

// --- Kernel 1: sign(W) -> +-1.0 bf16, fused with |W| partial reduction ---
__global__ __launch_bounds__(256) void k_convert_w(const float* __restrict__ w,
                                                   unsigned short* __restrict__ wq,
                                                   float* __restrict__ partials) {
  const int n4 = (NDIM * KDIM) / 4;
  const int stride = gridDim.x * blockDim.x;
  float s = 0.f;
  for (int i = blockIdx.x * blockDim.x + threadIdx.x; i < n4; i += stride) {
    f32x4 v = ((const f32x4*)w)[i];
    s += fabsf(v.x) + fabsf(v.y) + fabsf(v.z) + fabsf(v.w);
    us4 q;
    q.x = v.x > 0.f ? 0x3F80u : (v.x < 0.f ? 0xBF80u : 0u);
    q.y = v.y > 0.f ? 0x3F80u : (v.y < 0.f ? 0xBF80u : 0u);
    q.z = v.z > 0.f ? 0x3F80u : (v.z < 0.f ? 0xBF80u : 0u);
    q.w = v.w > 0.f ? 0x3F80u : (v.w < 0.f ? 0xBF80u : 0u);
    ((us4*)wq)[i] = q;
  }
  #pragma unroll
  for (int off = 32; off > 0; off >>= 1) s += __shfl_down(s, off, 64);
  __shared__ float red[4];
  if ((threadIdx.x & 63) == 0) red[threadIdx.x >> 6] = s;
  __syncthreads();
  if (threadIdx.x == 0) partials[blockIdx.x] = red[0] + red[1] + red[2] + red[3];
}

// --- Kernel 2: deterministic final reduction -> scale ---
__global__ __launch_bounds__(256) void k_scale(const float* __restrict__ partials,
                                               float* __restrict__ scale) {
  float s = 0.f;
  for (int i = threadIdx.x; i < NBLK_W; i += 256) s += partials[i];
  #pragma unroll
  for (int off = 32; off > 0; off >>= 1) s += __shfl_down(s, off, 64);
  __shared__ float red[4];
  if ((threadIdx.x & 63) == 0) red[threadIdx.x >> 6] = s;
  __syncthreads();
  if (threadIdx.x == 0)
    *scale = (red[0] + red[1] + red[2] + red[3]) / (float)((size_t)NDIM * KDIM);
}

// --- Kernel 3: x fp32 -> bf16 ---
__global__ __launch_bounds__(256) void k_convert_x(const float* __restrict__ x,
                                                   unsigned short* __restrict__ xb) {
  const int n8 = (MDIM * KDIM) / 8;
  const int stride = gridDim.x * blockDim.x;
  for (int i = blockIdx.x * blockDim.x + threadIdx.x; i < n8; i += stride) {
    f32x4 v0 = ((const f32x4*)x)[2 * i];
    f32x4 v1 = ((const f32x4*)x)[2 * i + 1];
    us8 q;
    q[0] = f2bf(v0.x); q[1] = f2bf(v0.y); q[2] = f2bf(v0.z); q[3] = f2bf(v0.w);
    q[4] = f2bf(v1.x); q[5] = f2bf(v1.y); q[6] = f2bf(v1.z); q[7] = f2bf(v1.w);
    ((us8*)xb)[i] = q;
  }
}

// --- Kernel 4: 256x256 8-phase GEMM, r9 skeleton + 32x32x16 MFMA ---
// C[m][n] = scale * sum_k A[m][k]*Bq[n][k] + bias[n]
// 8 waves (2M x 4N), per-wave 128x64 = 4 Mtiles(32) x 2 Ntiles(32).
// r9's MFMA-first single-barrier phases kept EXACTLY; only the MFMA shape
// changes: v_mfma_f32_32x32x16_bf16 (2382 vs 2075 TF ubench, half the
// instructions). Per phase: 8 MFMAs = 1 quadrant (MQ in {0,2} Mtile-pair x
// 1 Ntile) x 4 k-steps(16).
// Frag layout (m74/m101): A: row=lane&31, k=(lane>>5)*8+[0..8); B same with
// col=lane&31; C/D: col=lane&31, row=(reg&3)+8*(reg>>2)+4*(lane>>5).
// Regs: acc 4x2xf32x16=128; af[2][4]+bq0[4]+bq1[4]=64 VGPR (same as r9).
// Load map (1 phase ahead): g0:bq1(b0) g1:af<-MQ1(b0) g2:- g3:af<-MQ0(b1),
//   bq0(b1) g4:bq1(b1) g5:af<-MQ1(b1) g6:- g7:af<-MQ0(b0'),bq0(b0').
// Stage slots: g0/g1 buf1.A<-K(2i+1); g2/g3 buf0.B<-K(2i+2);
//   g4/g5 buf0.A<-K(2i+2); g6/g7 buf1.B<-K(2i+3). VM(2) before BAR at g2/g6
//   (ledger: 10 outstanding -> retires the full buffer the next reads touch;
//   never 0 in-loop). WAR: every staged region's readers consumed >=1 barrier
//   earlier (lifetimes identical to r9). No other loop VMEM (no spill; watch
//   WRITE_SIZE ~= 352 MB).
// SWIZZLE: unchanged 3-bit XOR in the 64-short row; read col =
//   (kk*16 + (lane>>5)*8) ^ ((lane&7)<<3) -- granule (2kk+hi)^(row&7) is
//   uniform over banks (expect SQ_LDS_BANK_CONFLICT ~ 0; spike => revert).

#define BAR()  __builtin_amdgcn_s_barrier()
#define SB0()  __builtin_amdgcn_sched_barrier(0)
#define PRIO1() __builtin_amdgcn_s_setprio(1)
#define PRIO0() __builtin_amdgcn_s_setprio(0)
#define VM(N)  asm volatile("s_waitcnt vmcnt(" #N ")" ::: "memory")

#define STAGE(GP, ROWB, LDSOFF, HALF, KT) do {                                        \
  const unsigned short* _s = (GP) + (size_t)((ROWB) + (HALF)*128 + srow) * KDIM       \
                              + (KT)*64 + scol;                                       \
  unsigned short* _d = lds + (LDSOFF) + (HALF)*8192 + tid*8;                          \
  __builtin_amdgcn_global_load_lds((const GAS unsigned int*)_s,                       \
                                   (LAS unsigned int*)_d, 16, 0, 0);                  \
  __builtin_amdgcn_global_load_lds((const GAS unsigned int*)(_s + (size_t)64*KDIM),   \
                                   (LAS unsigned int*)(_d + 4096), 16, 0, 0);         \
} while (0)

// B frags for one 32-col Ntile: DST[kk], kk = k-step of 16
#define LOAD_B1(DST, BUF, NB)                                                         \
  _Pragma("unroll") for (int kk = 0; kk < 4; ++kk)                                    \
    DST[kk] = *(const bf16x8*)&lds[(BUF)*32768 + 16384 + bWOff + (NB)*2048            \
                                   + rowoff + rcol[kk]];

// A frags for one 64-row Mtile-pair (MQ=0 rows 0-63, MQ=1 rows 64-127 of half)
#define LOAD_A(DST, BUF, MQ)                                                          \
  _Pragma("unroll") for (int mi = 0; mi < 2; ++mi)                                    \
  _Pragma("unroll") for (int kk = 0; kk < 4; ++kk)                                    \
    DST[mi][kk] = *(const bf16x8*)&lds[(BUF)*32768 + aWOff + (MQ)*4096 + mi*2048      \
                                       + rowoff + rcol[kk]];

// 8 MFMA (32x32x16): 4 kk x 2 mi -> acc[MB+mi][NB]; per-acc dep distance 2
#define MFMA8(AF, MB, BQ, NB)                                                         \
  _Pragma("unroll") for (int kk = 0; kk < 4; ++kk)                                    \
  _Pragma("unroll") for (int mi = 0; mi < 2; ++mi)                                    \
    acc[(MB)+mi][NB] = __builtin_amdgcn_mfma_f32_32x32x16_bf16(                       \
        AF[mi][kk], BQ[kk], acc[(MB)+mi][NB], 0, 0, 0);

__global__ __launch_bounds__(512, 2) void k_gemm256(const unsigned short* __restrict__ A,
                                                    const unsigned short* __restrict__ B,
                                                    const float* __restrict__ bias,
                                                    const float* __restrict__ scale_p,
                                                    float* __restrict__ C) {
  extern __shared__ unsigned short lds[];

  const int nTn = NDIM / 256;                  // 43
  const int nwg = (MDIM / 256) * nTn;          // 1376 (== 0 mod 8)
  int wg = (int)blockIdx.x;
  wg = (wg & 7) * (nwg / 8) + (wg >> 3);       // XCD-aware swizzle (bijective)
  const int tm = wg / nTn;
  const int tn = wg % nTn;

  const int tid  = (int)threadIdx.x;
  const int lane = tid & 63;
  const int wave = tid >> 6;                   // 0..7
  const int wm   = wave >> 2;                  // 0..1  (M)
  const int wn   = wave & 3;                   // 0..3  (N)
  const int l31  = lane & 31;

  // read-side (32x32 frags): row = lane&31, col = (kk*16 + (lane>>5)*8) ^ ((lane&7)<<3)
  const int rowoff = l31 * 64;
  const int rsw = (lane & 7) << 3;
  const int hi8 = (lane >> 5) * 8;
  int rcol[4];
  #pragma unroll
  for (int kk = 0; kk < 4; ++kk) rcol[kk] = (kk * 16 + hi8) ^ rsw;
  // stage-side: LDS linear dest; pre-swizzled GLOBAL source column (rule #21)
  const int scol = ((tid & 7) * 8) ^ (((tid >> 3) & 7) << 3);
  const int srow = tid >> 3;                   // 0..63

  const int aWOff = wm * 8192;                             // this wave's A half
  const int bWOff = (wn >> 1) * 8192 + (wn & 1) * 4096;    // this wave's 64-row B chunk
  const int aRow = tm * 256;
  const int bRow = tn * 256;

  f32x16 acc[4][2];
  #pragma unroll
  for (int i = 0; i < 4; ++i)
    #pragma unroll
    for (int j = 0; j < 2; ++j)
      #pragma unroll
      for (int e = 0; e < 16; ++e) acc[i][j][e] = 0.f;

  bf16x8 af[2][4], bq0[4], bq1[4];

  // ---- prologue: K0 -> buf0 (B,A); K1.B -> buf1; pre-load g0's operands ----
  STAGE(B, bRow, 16384, 0, 0);
  STAGE(B, bRow, 16384, 1, 0);
  STAGE(A, aRow, 0,     0, 0);
  STAGE(A, aRow, 0,     1, 0);
  STAGE(B, bRow, 49152, 0, 1);
  STAGE(B, bRow, 49152, 1, 1);
  VM(4);                                        // buf0 K0 fully landed
  SB0();
  BAR();
  LOAD_A(af, 0, 0); LOAD_B1(bq0, 0, 0);         // operands for g0

  #pragma unroll 1
  for (int i = 0; i < 32; ++i) {
    const int kA = 2 * i + 1;                            // <= 63
    const int kB = (2 * i + 2 > 63) ? 63 : 2 * i + 2;    // clamped tail
    const int kC = (2 * i + 3 > 63) ? 63 : 2 * i + 3;
    // g0: MFMA(MQ0,N0)@b0; load bq1(b0) for g1; stage buf1.A.h0 <- kA
    PRIO1(); MFMA8(af, 0, bq0, 0); PRIO0(); SB0();
    LOAD_B1(bq1, 0, 1);
    STAGE(A, aRow, 32768, 0, kA);
    BAR();
    // g1: MFMA(MQ0,N1); load af<-MQ1(b0) for g2 (WAR-pinned); stage buf1.A.h1
    PRIO1(); MFMA8(af, 0, bq1, 1); PRIO0(); SB0();
    LOAD_A(af, 0, 1);
    STAGE(A, aRow, 32768, 1, kA);
    BAR();
    // g2: MFMA(MQ1,N0); no loads; stage buf0.B.h0 <- kB; VM(2) confirms buf1
    PRIO1(); MFMA8(af, 2, bq0, 0); PRIO0(); SB0();
    STAGE(B, bRow, 16384, 0, kB);
    VM(2); SB0();
    BAR();
    // g3: MFMA(MQ1,N1); load af<-MQ0(b1) + bq0(b1) for g4; stage buf0.B.h1
    PRIO1(); MFMA8(af, 2, bq1, 1); PRIO0(); SB0();
    LOAD_A(af, 1, 0); LOAD_B1(bq0, 1, 0);
    STAGE(B, bRow, 16384, 1, kB);
    BAR();
    // g4: MFMA(MQ0,N0)@b1; load bq1(b1) for g5; stage buf0.A.h0 <- kB
    PRIO1(); MFMA8(af, 0, bq0, 0); PRIO0(); SB0();
    LOAD_B1(bq1, 1, 1);
    STAGE(A, aRow, 0, 0, kB);
    BAR();
    // g5: MFMA(MQ0,N1); load af<-MQ1(b1) for g6; stage buf0.A.h1
    PRIO1(); MFMA8(af, 0, bq1, 1); PRIO0(); SB0();
    LOAD_A(af, 1, 1);
    STAGE(A, aRow, 0, 1, kB);
    BAR();
    // g6: MFMA(MQ1,N0); no loads; stage buf1.B.h0 <- kC; VM(2) confirms buf0
    PRIO1(); MFMA8(af, 2, bq0, 0); PRIO0(); SB0();
    STAGE(B, bRow, 49152, 0, kC);
    VM(2); SB0();
    BAR();
    // g7: MFMA(MQ1,N1); load af<-MQ0(b0') + bq0(b0') for next g0; stage buf1.B.h1
    PRIO1(); MFMA8(af, 2, bq1, 1); PRIO0(); SB0();
    LOAD_A(af, 0, 0); LOAD_B1(bq0, 0, 0);
    STAGE(B, bRow, 49152, 1, kC);
    BAR();
  }

  VM(0);  // drain tail prefetch stages before epilogue

  const float sc = *scale_p;
  float bv[2];
  #pragma unroll
  for (int ni = 0; ni < 2; ++ni) bv[ni] = bias[tn * 256 + wn * 64 + ni * 32 + l31];

  // C/D layout (32x32, m74/m101): col = lane&31, row = (r&3)+8*(r>>2)+4*(lane>>5)
  #pragma unroll
  for (int mi = 0; mi < 4; ++mi) {
    #pragma unroll
    for (int r = 0; r < 16; ++r) {
      const int crow = (r & 3) + 8 * (r >> 2) + 4 * (lane >> 5);
      const int m = tm * 256 + wm * 128 + mi * 32 + crow;
      float* crowp = C + (size_t)m * NDIM + tn * 256 + wn * 64;
      #pragma unroll
      for (int ni = 0; ni < 2; ++ni)
        crowp[ni * 32 + l31] = sc * acc[mi][ni][r] + bv[ni];
    }
  }
}

extern "C" void kernel_launch(void* const* d_in, const int* in_sizes, int n_in,
                              void* d_out, int out_size, void* d_ws, size_t ws_size,
                              hipStream_t stream) {
  const float* x = (const float*)d_in[0];
  const float* w = (const float*)d_in[1];
  const float* bias = (const float*)d_in[2];
  float* out = (float*)d_out;

  char* ws = (char*)d_ws;
  const size_t XB_BYTES = (size_t)MDIM * KDIM * 2;
  const size_t WQ_BYTES = (size_t)NDIM * KDIM * 2;
  unsigned short* xb = (unsigned short*)ws;
  unsigned short* wq = (unsigned short*)(ws + XB_BYTES);
  float* partials = (float*)(ws + XB_BYTES + WQ_BYTES);
  float* scale = partials + NBLK_W;

  k_convert_w<<<NBLK_W, 256, 0, stream>>>(w, wq, partials);
  k_scale<<<1, 256, 0, stream>>>(partials, scale);
  k_convert_x<<<NBLK_X, 256, 0, stream>>>(x, xb);

  (void)hipFuncSetAttribute((const void*)k_gemm256,
                            hipFuncAttributeMaxDynamicSharedMemorySize, 131072);
  const int grid = (MDIM / 256) * (NDIM / 256);  // 1376
  k_gemm256<<<grid, 512, 131072, stream>>>(xb, wq, bias, scale, out);
}